// Round 6
// baseline (6720.053 us; speedup 1.0000x reference)
//
#include <hip/hip_runtime.h>

// RecurrentEncoder: proj(16->512)+relu, 3-layer LSTM (H=512), out head (512->16).
// B=256, T=128. Round 6: persistent kernel (192 WGs x 128 thr, 1 WG/CU via 128 KB
// LDS; co-residency proven round 2). W in LDS all 128 steps; c-state in regs;
// verified 32x32x16 swapped-operand MFMA. Cross-WG h exchange via VOLATILE
// loads/stores (cache-bypass bits, compiler-managed registers -- no inline-asm
// async loads, which caused rounds 4/5's spill-corruption hang). Flag protocol =
// round-2's proven one (tid0 spin + syncthreads broadcast), bounded spins.

typedef __attribute__((ext_vector_type(8)))  short bf16x8;
typedef __attribute__((ext_vector_type(16))) float f32x16;
typedef __attribute__((ext_vector_type(4)))  float f32x4;
typedef __attribute__((ext_vector_type(8)))  unsigned short us8;

#define B_  256
#define T_  128
#define FIN 16
#define H_  512
#define G4  2048
#define MF(A,B,C) __builtin_amdgcn_mfma_f32_32x32x16_bf16(A,B,C,0,0,0)

static __device__ __forceinline__ float bf2f(unsigned short u){
  return __uint_as_float(((unsigned)u) << 16);
}
static __device__ __forceinline__ unsigned short f2bf(float f){  // RNE
  unsigned u = __float_as_uint(f);
  u += 0x7fffu + ((u >> 16) & 1u);
  return (unsigned short)(u >> 16);
}
static __device__ __forceinline__ float sigm(float x){ return 1.f/(1.f + __expf(-x)); }
static __device__ __forceinline__ float tanh_(float x){ return 1.f - 2.f/(__expf(2.f*x) + 1.f); }

// Bounded relaxed spin (caller: tid==0 only, then __syncthreads). Bound makes a
// desync a wrong answer (diagnosable), never a 600 s timeout: ~3 ms worst case.
static __device__ __forceinline__ void spin_ge(int* p, int v){
  int guard = 0;
  while (__hip_atomic_load(p, __ATOMIC_RELAXED, __HIP_MEMORY_SCOPE_AGENT) < v &&
         guard++ < (1 << 14))
    __builtin_amdgcn_s_sleep(4);
}

// ================= prep kernels (verified rounds 1-3) =================

// lstm_w fp32 [3][1024][2048] -> bf16, 32x32x16 A-frag order:
// wf[l][Jb=64][s=64][lane=64][e=8]; j' = Jb*32+(lane&31) (j' = hcol*4+gate),
// k = s*16 + (lane>>5)*8 + e.
__global__ __launch_bounds__(256) void k_wconv(const float* __restrict__ w,
                                               unsigned short* __restrict__ wfo){
  long idx = (long)blockIdx.x*256 + threadIdx.x;   // 786432 = 3*64*64*64
  int lane = (int)(idx & 63);
  int s    = (int)((idx >> 6) & 63);
  int Jb   = (int)((idx >> 12) & 63);
  int l    = (int)(idx >> 18);
  int jp = Jb*32 + (lane & 31);
  int co = (jp & 3)*512 + (jp >> 2);       // orig col = gate*512 + hcol
  int k0 = s*16 + (lane >> 5)*8;
  us8 o;
  #pragma unroll
  for (int e = 0; e < 8; ++e)
    o[e] = f2bf(w[((long)(l*1024 + k0 + e))*2048 + co]);
  *(us8*)(wfo + idx*8) = o;
}

// xp = relu(x @ pw + pb) -> bf16, t-major: xpall[t][b][512]
__global__ __launch_bounds__(256) void k_xp(const float* __restrict__ x,
                                            const float* __restrict__ pw,
                                            const float* __restrict__ pb,
                                            unsigned short* __restrict__ xpall){
  __shared__ float sw[FIN*H_];
  __shared__ float sb[H_];
  int tid = threadIdx.x;
  for (int i = tid; i < FIN*H_; i += 256) sw[i] = pw[i];
  for (int i = tid; i < H_;     i += 256) sb[i] = pb[i];
  __syncthreads();
  int r0 = blockIdx.x * 64;
  int c0 = tid * 2;
  for (int rr = 0; rr < 64; ++rr){
    int r = r0 + rr;                       // flat b*T + t
    int b = r >> 7, t = r & 127;
    const float* xr = x + (long)r*FIN;
    float a0 = sb[c0], a1 = sb[c0+1];
    #pragma unroll
    for (int f = 0; f < FIN; ++f){
      float xv = xr[f];
      a0 += xv * sw[f*H_ + c0];
      a1 += xv * sw[f*H_ + c0 + 1];
    }
    ushort2 tmp;
    tmp.x = f2bf(fmaxf(a0, 0.f));
    tmp.y = f2bf(fmaxf(a1, 0.f));
    *(ushort2*)(xpall + ((long)t*256 + b)*512 + c0) = tmp;
  }
}

// y = h2all @ out_w + out_b ; h2all t-major [t][256][512] (verified round 3)
__global__ __launch_bounds__(256) void k_out(const unsigned short* __restrict__ h2,
                                             const float* __restrict__ ow,
                                             const float* __restrict__ ob,
                                             float* __restrict__ dout){
  __shared__ float sw[H_*16];
  int tid = threadIdx.x;
  for (int i = tid; i < H_*16; i += 256) sw[i] = ow[i];
  __syncthreads();
  int r0 = blockIdx.x * 128;
  #pragma unroll
  for (int q = 0; q < 8; ++q){
    int oid = tid + 256*q;
    int rr = oid >> 4, o = oid & 15;
    int r = r0 + rr;                        // flat b*T + t
    int b = r >> 7, t = r & 127;
    const us8* hp = (const us8*)(h2 + ((long)t*256 + b)*512);
    float acc = ob[o];
    for (int k8 = 0; k8 < H_/8; ++k8){
      us8 v = hp[k8];
      #pragma unroll
      for (int e = 0; e < 8; ++e) acc += bf2f(v[e]) * sw[(k8*8 + e)*16 + o];
    }
    dout[(long)r*16 + o] = acc;
  }
}

// ================= persistent RNN kernel =================

#define CELLP(ACC, JB, RF) \
  { _Pragma("unroll") \
    for (int q = 0; q < 4; ++q){ \
      float iv = ACC[4*q+0], gv = ACC[4*q+1], fv = ACC[4*q+2], ov = ACC[4*q+3]; \
      float cp = cst[JB][RF][q]; \
      float cn = sigm(fv + 1.f)*cp + sigm(iv)*tanh_(gv); \
      float hn = sigm(ov)*tanh_(cn); \
      cst[JB][RF][q] = cn; \
      int row = row0 + RF*32 + l31; \
      int hc  = (n*2 + JB)*8 + 2*q + l5; \
      unsigned short hv = f2bf(hn); \
      hw[(long)row*512 + hc] = hv; \
      if (l < 2) hrw[(long)row*512 + hc] = f2bf(fmaxf(hn, 0.f)); \
      else h2all[((long)t*256 + row)*512 + hc] = hv; \
    } }

// Volatile 16B loads: compiler-tracked (safe regalloc + correct waitcnts),
// cache-bypass bits set by the memory legalizer -> reads the coherence point.
#define LOADG(V, G) { \
  V##0 = *(const volatile bf16x8*)(p0 + ((G)*4+0)*16); \
  V##1 = *(const volatile bf16x8*)(p1 + ((G)*4+0)*16); \
  V##2 = *(const volatile bf16x8*)(p0 + ((G)*4+1)*16); \
  V##3 = *(const volatile bf16x8*)(p1 + ((G)*4+1)*16); \
  V##4 = *(const volatile bf16x8*)(p0 + ((G)*4+2)*16); \
  V##5 = *(const volatile bf16x8*)(p1 + ((G)*4+2)*16); \
  V##6 = *(const volatile bf16x8*)(p0 + ((G)*4+3)*16); \
  V##7 = *(const volatile bf16x8*)(p1 + ((G)*4+3)*16); }

#define MSTEP(I, B0, B1) { \
  bf16x8 w0 = *(const bf16x8*)(Wl + (((sbase+(I))*64 + lane) << 4)); \
  bf16x8 w1 = *(const bf16x8*)(Wl + ((4096 + (sbase+(I))*64 + lane) << 4)); \
  a00 = MF(w0, B0, a00); a01 = MF(w0, B1, a01); \
  a10 = MF(w1, B0, a10); a11 = MF(w1, B1, a11); }

#define CONSG(V, G) MSTEP((G)*4+0, V##0, V##1) MSTEP((G)*4+1, V##2, V##3) \
                    MSTEP((G)*4+2, V##4, V##5) MSTEP((G)*4+3, V##6, V##7)

// 3-deep source-level pipeline, all names compile-time (rule 20 safe).
#define GEMM_HALF { \
  LOADG(vA,0) LOADG(vB,1) LOADG(vC,2) \
  CONSG(vA,0) LOADG(vA,3) \
  CONSG(vB,1) LOADG(vB,4) \
  CONSG(vC,2) LOADG(vC,5) \
  CONSG(vA,3) LOADG(vA,6) \
  CONSG(vB,4) LOADG(vB,7) \
  CONSG(vC,5) CONSG(vA,6) CONSG(vB,7) }

// grid 192 = l(3) x mg(2) x n(32); block 128 (2 waves, wave = 64 rows).
// LDS: W slice [jb=2][s=64][lane=64][16B] = 128 KB -> 1 WG/CU, all co-resident.
__global__ __launch_bounds__(128, 1) void k_rnn(
    const unsigned short* __restrict__ wf, const float* __restrict__ lb,
    unsigned short* hb, unsigned short* hrl,
    const unsigned short* __restrict__ xpall, unsigned short* __restrict__ h2all,
    int* flags)
{
  extern __shared__ unsigned char Wl[];    // 131072 B
  const int tid = threadIdx.x;
  const int wg  = blockIdx.x;
  const int l   = wg >> 6;
  const int rem = wg & 63;
  const int n   = rem & 31;
  const int mg  = rem >> 5;
  const int lane = tid & 63;
  const int wv   = tid >> 6;
  const int l5 = lane >> 5, l31 = lane & 31;
  const int row0 = mg*128 + wv*64;

  // ---- preload W slice into LDS (once) ----
  {
    const us8* src = (const us8*)(wf + ((long)(l*64 + n*2))*4096*8);
    us8* dst = (us8*)Wl;
    for (int i = tid; i < 8192; i += 128) dst[i] = src[i];
  }
  // ---- bias acc-init vectors (D frag: row j'_local = (r&3)+8*(r>>2)+4*l5) ----
  f32x16 bias0, bias1;
  #pragma unroll
  for (int r = 0; r < 16; ++r){
    int hc0 = (n*2 + 0)*8 + 2*(r>>2) + l5;
    int hc1 = (n*2 + 1)*8 + 2*(r>>2) + l5;
    bias0[r] = lb[l*G4 + (r&3)*512 + hc0];
    bias1[r] = lb[l*G4 + (r&3)*512 + hc1];
  }
  float cst[2][2][4] = {};                 // register c-state
  __syncthreads();

  int* fOwn  = flags + (l*2 + mg);
  int* fPrev = flags + ((l-1)*2 + mg);
  int* fNext = flags + ((l+1)*2 + mg);

  bf16x8 vA0,vA1,vA2,vA3,vA4,vA5,vA6,vA7;
  bf16x8 vB0,vB1,vB2,vB3,vB4,vB5,vB6,vB7;
  bf16x8 vC0,vC1,vC2,vC3,vC4,vC5,vC6,vC7;

  for (int t = 0; t < T_; ++t){
    const int pw = t & 1, pr = pw ^ 1;
    // W1: own group done step t-1 (h[l][t-1] ready + WAR on hb[pw]).
    // W3: group l+1 done step t-2 (WAR on hrl[pw] we overwrite below).
    if (t > 0){
      if (tid == 0){
        spin_ge(fOwn, 32*t);
        if (l < 2 && t >= 2) spin_ge(fNext, 32*(t-1));
      }
      __syncthreads();
    }

    f32x16 a00 = bias0, a01 = bias0, a10 = bias1, a11 = bias1;

    // ---- right half: k in [512,1024) = own h_prev (coherent volatile reads) ----
    {
      const volatile unsigned short* p0 =
          hb + (((long)(pr*3 + l))*256 + row0 + l31)*512 + l5*8;
      const volatile unsigned short* p1 = p0 + 32*512;
      const int sbase = 32;
      GEMM_HALF
    }
    // W2: layer below finished step t (left input ready)
    if (l > 0){
      if (tid == 0) spin_ge(fPrev, 32*(t+1));
      __syncthreads();
    }
    // ---- left half: k in [0,512) = xp[t] (l==0) or relu(h[l-1][t]) ----
    {
      const unsigned short* lsrc = (l == 0)
          ? xpall + (long)t*256*512
          : hrl + (long)(pw*2 + (l-1))*256*512;
      const volatile unsigned short* p0 = lsrc + ((long)(row0 + l31))*512 + l5*8;
      const volatile unsigned short* p1 = p0 + 32*512;
      const int sbase = 0;
      GEMM_HALF
    }
    // ---- LSTM cell in regs; h/hrelu stores volatile (write-through) ----
    {
      volatile unsigned short* hw  = hb + (long)(pw*3 + l)*256*512;
      volatile unsigned short* hrw = (l < 2)
          ? (hrl + (long)(pw*2 + l)*256*512) : (volatile unsigned short*)0;
      CELLP(a00, 0, 0)
      CELLP(a01, 0, 1)
      CELLP(a10, 1, 0)
      CELLP(a11, 1, 1)
    }
    // barrier drains both waves' vmcnt (compiler emits full waitcnt before
    // s_barrier) -> all h stores are at the coherence point before the bump.
    __syncthreads();
    if (tid == 0)
      __hip_atomic_fetch_add(fOwn, 1, __ATOMIC_RELAXED, __HIP_MEMORY_SCOPE_AGENT);
  }
}

// ================= round-0 fallback (compact) kernels =================

__global__ __launch_bounds__(256) void k_wconv0(const float* __restrict__ w,
                                                unsigned short* __restrict__ wf){
  long d8 = ((long)blockIdx.x*256 + threadIdx.x) * 8;
  int lane = (int)((d8 >> 3) & 63);
  int s    = (int)((d8 >> 9) & 31);
  int J    = (int)((d8 >> 14) & 127);
  int l    = (int)(d8 >> 21);
  int jj = lane & 15, khi = lane >> 4;
  int jp = J*16 + jj;
  int co = (jp & 3)*512 + (jp >> 2);
  int kbase = s*32 + khi*8;
  us8 o;
  #pragma unroll
  for (int e = 0; e < 8; ++e)
    o[e] = f2bf(w[((long)(l*1024 + kbase + e))*2048 + co]);
  *(us8*)(wf + d8) = o;
}

__global__ void k_iout(float* __restrict__ dout, const float* __restrict__ ob){
  int i = blockIdx.x*256 + threadIdx.x;
  if (i < B_*T_*16) dout[i] = ob[i & 15];
}

__global__ __launch_bounds__(256, 2) void k_stage0(
    const float* __restrict__ x, const float* __restrict__ pw, const float* __restrict__ pb,
    const unsigned short* __restrict__ wf, const float* __restrict__ lb,
    const float* __restrict__ ow, float* __restrict__ dout,
    float* __restrict__ cbuf, unsigned short* __restrict__ hb,
    int t, int l)
{
  __shared__ unsigned char Ab[32*2048];
  __shared__ float gsm[32*36];
  __shared__ float xrow[32*16];
  __shared__ float hcell[32*8];

  const int tid = threadIdx.x;
  const int bid = blockIdx.x;
  const int m = bid >> 6;
  const int n = ((bid & 7) << 3) | ((bid >> 3) & 7);
  const int pwr = t & 1, prd = pwr ^ 1;
  const int bg0 = m * 32;

  {
    const unsigned short* src = hb + (((long)prd*3 + l)*256 + bg0)*512;
    for (int i = 0; i < 8; ++i){
      int cid = tid + 256*i;
      int row = cid >> 6, cc = cid & 63;
      us8 v = *(const us8*)(src + (long)row*512 + cc*8);
      *(us8*)(Ab + ((row*2048 + 1024 + cc*16) ^ ((row & 7) << 4))) = v;
    }
  }
  if (l > 0){
    const unsigned short* src = hb + (((long)pwr*3 + (l-1))*256 + bg0)*512;
    for (int i = 0; i < 8; ++i){
      int cid = tid + 256*i;
      int row = cid >> 6, cc = cid & 63;
      us8 v = *(const us8*)(src + (long)row*512 + cc*8);
      #pragma unroll
      for (int e = 0; e < 8; ++e) v[e] = (v[e] & 0x8000u) ? (unsigned short)0 : v[e];
      *(us8*)(Ab + ((row*2048 + cc*16) ^ ((row & 7) << 4))) = v;
    }
  } else {
    {
      int e2 = tid*2;
      int br = e2 >> 4, f = e2 & 15;
      const float* xr = x + ((long)(bg0 + br)*T_ + t)*FIN;
      xrow[e2] = xr[f]; xrow[e2+1] = xr[f+1];
    }
    __syncthreads();
    for (int i = 0; i < 8; ++i){
      int cid = tid + 256*i;
      int row = cid >> 6, cc = cid & 63;
      int c0 = cc*8;
      us8 vv;
      #pragma unroll
      for (int j = 0; j < 8; ++j){
        float a = pb[c0 + j];
        #pragma unroll
        for (int f = 0; f < FIN; ++f) a += xrow[row*16 + f] * pw[f*H_ + c0 + j];
        vv[j] = f2bf(fmaxf(a, 0.f));
      }
      *(us8*)(Ab + ((row*2048 + cc*16) ^ ((row & 7) << 4))) = vv;
    }
  }
  __syncthreads();

  const int lane = tid & 63, wid = tid >> 6;
  const int wm = wid >> 1, wn = wid & 1;
  const int J = n*2 + wn;
  const int arow = wm*16 + (lane & 15);
  const unsigned abase = (unsigned)arow*2048 + ((lane >> 4) << 4);
  const unsigned axor = (unsigned)((arow & 7) << 4);
  const unsigned short* bp = wf + ((((long)l*128 + J)*32)*64 + lane)*8;

  f32x4 acc = {0.f, 0.f, 0.f, 0.f};
  #pragma unroll
  for (int s = 0; s < 32; ++s){
    bf16x8 af = *(const bf16x8*)(Ab + ((abase + s*64) ^ axor));
    bf16x8 bfr = *(const bf16x8*)(bp + (long)s*512);
    acc = __builtin_amdgcn_mfma_f32_16x16x32_bf16(af, bfr, acc, 0, 0, 0);
  }
  {
    int colb = wn*16 + (lane & 15);
    int rowb = wm*16 + ((lane >> 4) << 2);
    #pragma unroll
    for (int r = 0; r < 4; ++r) gsm[(rowb + r)*36 + colb] = acc[r];
  }
  __syncthreads();

  {
    int bl = tid >> 3, hc = tid & 7;
    float4 g4 = *(float4*)(&gsm[bl*36 + hc*4]);
    int hcol = n*8 + hc;
    int bgl = bg0 + bl;
    float iv = g4.x + lb[l*G4 + hcol];
    float gv = g4.y + lb[l*G4 + 512 + hcol];
    float fv = g4.z + lb[l*G4 + 1024 + hcol];
    float ov = g4.w + lb[l*G4 + 1536 + hcol];
    long coff = ((long)l*256 + bgl)*512 + hcol;
    float cp = cbuf[coff];
    float cn = sigm(fv + 1.f)*cp + sigm(iv)*tanh_(gv);
    float hn = sigm(ov)*tanh_(cn);
    cbuf[coff] = cn;
    hb[(((long)pwr*3 + l)*256 + bgl)*512 + hcol] = f2bf(hn);
    if (l == 2) hcell[bl*8 + hc] = hn;
  }
  if (l == 2){
    __syncthreads();
    #pragma unroll
    for (int q = 0; q < 2; ++q){
      int oid = tid + 256*q;
      int bl = oid >> 4, o = oid & 15;
      float a = 0.f;
      #pragma unroll
      for (int hc = 0; hc < 8; ++hc) a += hcell[bl*8 + hc] * ow[(n*8 + hc)*16 + o];
      atomicAdd(dout + ((long)(bg0 + bl)*T_ + t)*16 + o, a);
    }
  }
}

// ================= launch =================

extern "C" void kernel_launch(void* const* d_in, const int* in_sizes, int n_in,
                              void* d_out, int out_size, void* d_ws, size_t ws_size,
                              hipStream_t stream)
{
  const float* x  = (const float*)d_in[0];
  const float* pw = (const float*)d_in[1];
  const float* pb = (const float*)d_in[2];
  const float* lw = (const float*)d_in[3];
  const float* lb = (const float*)d_in[4];
  const float* ow = (const float*)d_in[5];
  const float* ob = (const float*)d_in[6];
  float* dout = (float*)d_out;

  char* ws = (char*)d_ws;
  size_t off = 0;
  auto carve = [&](size_t bytes){ char* p = ws + off; off += (bytes + 255) & ~(size_t)255; return p; };
  unsigned short* wf    = (unsigned short*)carve(3ull*64*4096*8*2);    // 12.58 MB
  unsigned short* hbuf  = (unsigned short*)carve(2ull*3*256*512*2);    // 1.57 MB
  unsigned short* hrl   = (unsigned short*)carve(2ull*2*256*512*2);    // 1.05 MB
  int*            flags = (int*)carve(64);
  unsigned short* xpall = (unsigned short*)carve((size_t)B_*T_*H_*2);  // 33.55 MB
  unsigned short* h2all = (unsigned short*)carve((size_t)B_*T_*H_*2);  // 33.55 MB
  size_t need_lux = off;                                               // ~82.3 MB

  bool lux = (ws_size >= need_lux);
  if (lux)
    lux = (hipFuncSetAttribute((const void*)k_rnn,
                               hipFuncAttributeMaxDynamicSharedMemorySize,
                               131072) == hipSuccess);

  if (lux){
    // zero h (both parities) + hrelu + flags (contiguous carves)
    hipMemsetAsync(hbuf, 0, 2ull*3*256*512*2 + 2ull*2*256*512*2 + 256, stream);
    k_wconv<<<3072, 256, 0, stream>>>(lw, wf);
    k_xp<<<512, 256, 0, stream>>>(x, pw, pb, xpall);
    k_rnn<<<192, 128, 131072, stream>>>(wf, lb, hbuf, hrl, xpall, h2all, flags);
    k_out<<<256, 256, 0, stream>>>(h2all, ow, ob, dout);
  } else {
    // round-0 compact fallback (proven)
    size_t o2 = 0;
    auto carve2 = [&](size_t bytes){ char* p = ws + o2; o2 += (bytes + 255) & ~(size_t)255; return p; };
    unsigned short* wf0   = (unsigned short*)carve2(3ull*1024*2048*2);
    float*          cbuf0 = (float*)carve2(3ull*256*512*4);
    unsigned short* hbuf0 = (unsigned short*)carve2(2ull*3*256*512*2);
    hipMemsetAsync(cbuf0, 0, 3ull*256*512*4 + 2ull*3*256*512*2, stream);
    k_wconv0<<<3072, 256, 0, stream>>>(lw, wf0);
    k_iout<<<2048, 256, 0, stream>>>(dout, ob);
    for (int t = 0; t < T_; ++t)
      for (int l = 0; l < 3; ++l)
        k_stage0<<<512, 256, 0, stream>>>(x, pw, pb, wf0, lb, ow, dout,
                                          cbuf0, hbuf0, t, l);
  }
}

// Round 7
// 3055.332 us; speedup vs baseline: 2.1995x; 2.1995x over previous
//
#include <hip/hip_runtime.h>

// RecurrentEncoder: proj(16->512)+relu, 3-layer LSTM (H=512), out head (512->16).
// B=256, T=128. Round 7: persistent kernel (96 WGs x 256 thr, 1 WG/CU via 136 KB
// LDS). W in LDS all 128 steps (verified r2/r6); c-state in regs; verified
// 32x32x16 swapped-operand MFMA. NEW: h lives in a time-indexed RING (no address
// ever reused) -> producers write through to L3 (packed 16B volatile via LDS
// bounce), consumers use PLAIN CACHED loads (L1/L2 can't be stale for a
// never-before-seen address; L2 absorbs the x32 same-XCD read amplification).
// No fences, no WAR waits, no hrelu buffer (consumer applies relu in-reg).

typedef __attribute__((ext_vector_type(8)))  short bf16x8;
typedef __attribute__((ext_vector_type(16))) float f32x16;
typedef __attribute__((ext_vector_type(8)))  unsigned short us8;

#define B_  256
#define T_  128
#define FIN 16
#define H_  512
#define G4  2048
#define MF(A,B,C) __builtin_amdgcn_mfma_f32_32x32x16_bf16(A,B,C,0,0,0)

static __device__ __forceinline__ float bf2f(unsigned short u){
  return __uint_as_float(((unsigned)u) << 16);
}
static __device__ __forceinline__ unsigned short f2bf(float f){  // RNE
  unsigned u = __float_as_uint(f);
  u += 0x7fffu + ((u >> 16) & 1u);
  return (unsigned short)(u >> 16);
}
static __device__ __forceinline__ float sigm(float x){ return 1.f/(1.f + __expf(-x)); }
static __device__ __forceinline__ float tanh_(float x){ return 1.f - 2.f/(__expf(2.f*x) + 1.f); }

// Bounded relaxed spin (caller: tid==0, then __syncthreads broadcast).
static __device__ __forceinline__ void spin_ge(int* p, int v){
  int guard = 0;
  while (__hip_atomic_load(p, __ATOMIC_RELAXED, __HIP_MEMORY_SCOPE_AGENT) < v &&
         guard++ < (1 << 14))
    __builtin_amdgcn_s_sleep(4);
}

// ================= prep kernels (verified rounds 1-6) =================

// lstm_w fp32 [3][1024][2048] -> bf16, 32x32x16 A-frag order:
// wf[l][Jb=64][s=64][lane=64][e=8]; j' = Jb*32+(lane&31) (j' = hcol*4+gate),
// k = s*16 + (lane>>5)*8 + e.
__global__ __launch_bounds__(256) void k_wconv(const float* __restrict__ w,
                                               unsigned short* __restrict__ wfo){
  long idx = (long)blockIdx.x*256 + threadIdx.x;   // 786432 = 3*64*64*64
  int lane = (int)(idx & 63);
  int s    = (int)((idx >> 6) & 63);
  int Jb   = (int)((idx >> 12) & 63);
  int l    = (int)(idx >> 18);
  int jp = Jb*32 + (lane & 31);
  int co = (jp & 3)*512 + (jp >> 2);       // orig col = gate*512 + hcol
  int k0 = s*16 + (lane >> 5)*8;
  us8 o;
  #pragma unroll
  for (int e = 0; e < 8; ++e)
    o[e] = f2bf(w[((long)(l*1024 + k0 + e))*2048 + co]);
  *(us8*)(wfo + idx*8) = o;
}

// xp = relu(x @ pw + pb) -> bf16, t-major: xpall[t][b][512]
__global__ __launch_bounds__(256) void k_xp(const float* __restrict__ x,
                                            const float* __restrict__ pw,
                                            const float* __restrict__ pb,
                                            unsigned short* __restrict__ xpall){
  __shared__ float sw[FIN*H_];
  __shared__ float sb[H_];
  int tid = threadIdx.x;
  for (int i = tid; i < FIN*H_; i += 256) sw[i] = pw[i];
  for (int i = tid; i < H_;     i += 256) sb[i] = pb[i];
  __syncthreads();
  int r0 = blockIdx.x * 64;
  int c0 = tid * 2;
  for (int rr = 0; rr < 64; ++rr){
    int r = r0 + rr;                       // flat b*T + t
    int b = r >> 7, t = r & 127;
    const float* xr = x + (long)r*FIN;
    float a0 = sb[c0], a1 = sb[c0+1];
    #pragma unroll
    for (int f = 0; f < FIN; ++f){
      float xv = xr[f];
      a0 += xv * sw[f*H_ + c0];
      a1 += xv * sw[f*H_ + c0 + 1];
    }
    ushort2 tmp;
    tmp.x = f2bf(fmaxf(a0, 0.f));
    tmp.y = f2bf(fmaxf(a1, 0.f));
    *(ushort2*)(xpall + ((long)t*256 + b)*512 + c0) = tmp;
  }
}

// y = ring[t][2] @ out_w + out_b (verified structure; ring-slot addressing)
__global__ __launch_bounds__(256) void k_out(const unsigned short* __restrict__ ring,
                                             const float* __restrict__ ow,
                                             const float* __restrict__ ob,
                                             float* __restrict__ dout){
  __shared__ float sw[H_*16];
  int tid = threadIdx.x;
  for (int i = tid; i < H_*16; i += 256) sw[i] = ow[i];
  __syncthreads();
  int r0 = blockIdx.x * 128;
  #pragma unroll
  for (int q = 0; q < 8; ++q){
    int oid = tid + 256*q;
    int rr = oid >> 4, o = oid & 15;
    int r = r0 + rr;                        // flat b*T + t
    int b = r >> 7, t = r & 127;
    const us8* hp = (const us8*)(ring + (((long)t*3 + 2)*256 + b)*512);
    float acc = ob[o];
    for (int k8 = 0; k8 < H_/8; ++k8){
      us8 v = hp[k8];
      #pragma unroll
      for (int e = 0; e < 8; ++e) acc += bf2f(v[e]) * sw[(k8*8 + e)*16 + o];
    }
    dout[(long)r*16 + o] = acc;
  }
}

// ================= persistent RNN kernel =================

// cell writes h into the LDS staging tile [256 rows][16 hc-local]
#define CELLS(ACC, JB, RF) \
  { _Pragma("unroll") \
    for (int q = 0; q < 4; ++q){ \
      float iv = ACC[4*q+0], gv = ACC[4*q+1], fv = ACC[4*q+2], ov = ACC[4*q+3]; \
      float cp = cst[JB][RF][q]; \
      float cn = sigm(fv + 1.f)*cp + sigm(iv)*tanh_(gv); \
      float hn = sigm(ov)*tanh_(cn); \
      cst[JB][RF][q] = cn; \
      int row = row0 + RF*32 + l31; \
      int hcl = JB*8 + 2*q + l5; \
      hstage[row*16 + hcl] = f2bf(hn); \
    } }

// grid 96 = l(3) x n(32); block 256 (4 waves; wave wv -> rows wv*64..+63).
// LDS: W slice 128 KB + h stage 8 KB = 136 KB -> 1 WG/CU, all co-resident.
__global__ __launch_bounds__(256, 1) void k_rnn(
    const unsigned short* __restrict__ wf, const float* __restrict__ lb,
    unsigned short* ring, const unsigned short* __restrict__ xpall,
    int* flags)
{
  extern __shared__ unsigned char Wl[];    // 131072 + 8192
  unsigned short* hstage = (unsigned short*)(Wl + 131072);
  const int tid = threadIdx.x;
  const int wgid = blockIdx.x;
  const int l = wgid >> 5;
  const int n = wgid & 31;
  const int lane = tid & 63;
  const int wv   = tid >> 6;
  const int l5 = lane >> 5, l31 = lane & 31;
  const int row0 = wv * 64;

  // ---- preload W slice into LDS (once) ----
  {
    const us8* src = (const us8*)(wf + ((long)(l*64 + n*2))*4096*8);
    us8* dst = (us8*)Wl;
    for (int i = tid; i < 8192; i += 256) dst[i] = src[i];
  }
  // ---- bias acc-init (D frag: j'_local = (r&3)+8*(r>>2)+4*l5) ----
  f32x16 bias0, bias1;
  #pragma unroll
  for (int r = 0; r < 16; ++r){
    int hc0 = (n*2 + 0)*8 + 2*(r>>2) + l5;
    int hc1 = (n*2 + 1)*8 + 2*(r>>2) + l5;
    bias0[r] = lb[l*G4 + (r&3)*512 + hc0];
    bias1[r] = lb[l*G4 + (r&3)*512 + hc1];
  }
  float cst[2][2][4] = {};                 // register c-state
  __syncthreads();

  int* fOwn  = flags + l;
  int* fPrev = flags + (l - 1);

  for (int t = 0; t < T_; ++t){
    // W1: all 32 WGs of own layer finished step t-1 (h[l][t-1] complete).
    if (t > 0){
      if (tid == 0) spin_ge(fOwn, 32*t);
      __syncthreads();
      __builtin_amdgcn_sched_barrier(0);
    }

    f32x16 a00 = bias0, a01 = bias0, a10 = bias1, a11 = bias1;

    // ---- right half: k in [512,1024) = own h[t-1] from ring (cached loads;
    //      addresses never seen before -> no staleness possible). t==0: h=0, skip.
    if (t > 0){
      const unsigned short* p0 =
          ring + (((long)((t-1)*3 + l))*256 + row0 + l31)*512 + l5*8;
      const unsigned short* p1 = p0 + 32*512;
      #pragma unroll 8
      for (int s = 32; s < 64; ++s){
        bf16x8 w0 = *(const bf16x8*)(Wl + ((s*64 + lane) << 4));
        bf16x8 w1 = *(const bf16x8*)(Wl + ((4096 + s*64 + lane) << 4));
        bf16x8 b0 = *(const bf16x8*)(p0 + (s-32)*16);
        bf16x8 b1 = *(const bf16x8*)(p1 + (s-32)*16);
        a00 = MF(w0, b0, a00); a01 = MF(w0, b1, a01);
        a10 = MF(w1, b0, a10); a11 = MF(w1, b1, a11);
      }
    }
    // W2: layer below finished step t (left input ready in ring).
    if (l > 0){
      if (tid == 0) spin_ge(fPrev, 32*(t+1));
      __syncthreads();
      __builtin_amdgcn_sched_barrier(0);
    }
    // ---- left half: k in [0,512) = xp[t] (l==0) or relu(h[l-1][t]) ----
    {
      const unsigned short* lsrc = (l == 0)
          ? xpall + (long)t*256*512
          : ring + ((long)(t*3 + (l-1)))*256*512;
      const unsigned short* p0 = lsrc + ((long)(row0 + l31))*512 + l5*8;
      const unsigned short* p1 = p0 + 32*512;
      if (l == 0){
        #pragma unroll 8
        for (int s = 0; s < 32; ++s){
          bf16x8 w0 = *(const bf16x8*)(Wl + ((s*64 + lane) << 4));
          bf16x8 w1 = *(const bf16x8*)(Wl + ((4096 + s*64 + lane) << 4));
          bf16x8 b0 = *(const bf16x8*)(p0 + s*16);
          bf16x8 b1 = *(const bf16x8*)(p1 + s*16);
          a00 = MF(w0, b0, a00); a01 = MF(w0, b1, a01);
          a10 = MF(w1, b0, a10); a11 = MF(w1, b1, a11);
        }
      } else {
        #pragma unroll 8
        for (int s = 0; s < 32; ++s){
          bf16x8 w0 = *(const bf16x8*)(Wl + ((s*64 + lane) << 4));
          bf16x8 w1 = *(const bf16x8*)(Wl + ((4096 + s*64 + lane) << 4));
          bf16x8 b0 = *(const bf16x8*)(p0 + s*16);
          bf16x8 b1 = *(const bf16x8*)(p1 + s*16);
          #pragma unroll
          for (int e = 0; e < 8; ++e){      // relu on bf16: sign bit -> 0
            if (b0[e] < 0) b0[e] = 0;
            if (b1[e] < 0) b1[e] = 0;
          }
          a00 = MF(w0, b0, a00); a01 = MF(w0, b1, a01);
          a10 = MF(w1, b0, a10); a11 = MF(w1, b1, a11);
        }
      }
    }
    // ---- LSTM cell in regs -> LDS h-stage ----
    CELLS(a00, 0, 0)
    CELLS(a01, 0, 1)
    CELLS(a10, 1, 0)
    CELLS(a11, 1, 1)
    __syncthreads();
    // ---- packed 16B write-through stores into ring (2 per thread) ----
    {
      unsigned short* hdst = ring + ((long)(t*3 + l))*256*512 + n*16;
      #pragma unroll
      for (int c = tid; c < 512; c += 256){
        int row = c >> 1, half = c & 1;
        us8 v = *(const us8*)(hstage + row*16 + half*8);
        *(volatile us8*)(hdst + (long)row*512 + half*8) = v;
      }
    }
    __syncthreads();   // compiler drains vmcnt before s_barrier -> stores at L3
    if (tid == 0)
      __hip_atomic_fetch_add(fOwn, 1, __ATOMIC_RELAXED, __HIP_MEMORY_SCOPE_AGENT);
  }
}

// ================= round-0 fallback (compact) kernels =================

__global__ __launch_bounds__(256) void k_wconv0(const float* __restrict__ w,
                                                unsigned short* __restrict__ wf){
  long d8 = ((long)blockIdx.x*256 + threadIdx.x) * 8;
  int lane = (int)((d8 >> 3) & 63);
  int s    = (int)((d8 >> 9) & 31);
  int J    = (int)((d8 >> 14) & 127);
  int l    = (int)(d8 >> 21);
  int jj = lane & 15, khi = lane >> 4;
  int jp = J*16 + jj;
  int co = (jp & 3)*512 + (jp >> 2);
  int kbase = s*32 + khi*8;
  us8 o;
  #pragma unroll
  for (int e = 0; e < 8; ++e)
    o[e] = f2bf(w[((long)(l*1024 + kbase + e))*2048 + co]);
  *(us8*)(wf + d8) = o;
}

__global__ void k_iout(float* __restrict__ dout, const float* __restrict__ ob){
  int i = blockIdx.x*256 + threadIdx.x;
  if (i < B_*T_*16) dout[i] = ob[i & 15];
}

__global__ __launch_bounds__(256, 2) void k_stage0(
    const float* __restrict__ x, const float* __restrict__ pw, const float* __restrict__ pb,
    const unsigned short* __restrict__ wf, const float* __restrict__ lb,
    const float* __restrict__ ow, float* __restrict__ dout,
    float* __restrict__ cbuf, unsigned short* __restrict__ hb,
    int t, int l)
{
  __shared__ unsigned char Ab[32*2048];
  __shared__ float gsm[32*36];
  __shared__ float xrow[32*16];
  __shared__ float hcell[32*8];

  const int tid = threadIdx.x;
  const int bid = blockIdx.x;
  const int m = bid >> 6;
  const int n = ((bid & 7) << 3) | ((bid >> 3) & 7);
  const int pwr = t & 1, prd = pwr ^ 1;
  const int bg0 = m * 32;

  {
    const unsigned short* src = hb + (((long)prd*3 + l)*256 + bg0)*512;
    for (int i = 0; i < 8; ++i){
      int cid = tid + 256*i;
      int row = cid >> 6, cc = cid & 63;
      us8 v = *(const us8*)(src + (long)row*512 + cc*8);
      *(us8*)(Ab + ((row*2048 + 1024 + cc*16) ^ ((row & 7) << 4))) = v;
    }
  }
  if (l > 0){
    const unsigned short* src = hb + (((long)pwr*3 + (l-1))*256 + bg0)*512;
    for (int i = 0; i < 8; ++i){
      int cid = tid + 256*i;
      int row = cid >> 6, cc = cid & 63;
      us8 v = *(const us8*)(src + (long)row*512 + cc*8);
      #pragma unroll
      for (int e = 0; e < 8; ++e) v[e] = (v[e] & 0x8000u) ? (unsigned short)0 : v[e];
      *(us8*)(Ab + ((row*2048 + cc*16) ^ ((row & 7) << 4))) = v;
    }
  } else {
    {
      int e2 = tid*2;
      int br = e2 >> 4, f = e2 & 15;
      const float* xr = x + ((long)(bg0 + br)*T_ + t)*FIN;
      xrow[e2] = xr[f]; xrow[e2+1] = xr[f+1];
    }
    __syncthreads();
    for (int i = 0; i < 8; ++i){
      int cid = tid + 256*i;
      int row = cid >> 6, cc = cid & 63;
      int c0 = cc*8;
      us8 vv;
      #pragma unroll
      for (int j = 0; j < 8; ++j){
        float a = pb[c0 + j];
        #pragma unroll
        for (int f = 0; f < FIN; ++f) a += xrow[row*16 + f] * pw[f*H_ + c0 + j];
        vv[j] = f2bf(fmaxf(a, 0.f));
      }
      *(us8*)(Ab + ((row*2048 + cc*16) ^ ((row & 7) << 4))) = vv;
    }
  }
  __syncthreads();

  const int lane = tid & 63, wid = tid >> 6;
  const int wm = wid >> 1, wn = wid & 1;
  const int J = n*2 + wn;
  const int arow = wm*16 + (lane & 15);
  const unsigned abase = (unsigned)arow*2048 + ((lane >> 4) << 4);
  const unsigned axor = (unsigned)((arow & 7) << 4);
  const unsigned short* bp = wf + ((((long)l*128 + J)*32)*64 + lane)*8;

  typedef __attribute__((ext_vector_type(4))) float f32x4;
  f32x4 acc = {0.f, 0.f, 0.f, 0.f};
  #pragma unroll
  for (int s = 0; s < 32; ++s){
    bf16x8 af = *(const bf16x8*)(Ab + ((abase + s*64) ^ axor));
    bf16x8 bfr = *(const bf16x8*)(bp + (long)s*512);
    acc = __builtin_amdgcn_mfma_f32_16x16x32_bf16(af, bfr, acc, 0, 0, 0);
  }
  {
    int colb = wn*16 + (lane & 15);
    int rowb = wm*16 + ((lane >> 4) << 2);
    #pragma unroll
    for (int r = 0; r < 4; ++r) gsm[(rowb + r)*36 + colb] = acc[r];
  }
  __syncthreads();

  {
    int bl = tid >> 3, hc = tid & 7;
    float4 g4 = *(float4*)(&gsm[bl*36 + hc*4]);
    int hcol = n*8 + hc;
    int bgl = bg0 + bl;
    float iv = g4.x + lb[l*G4 + hcol];
    float gv = g4.y + lb[l*G4 + 512 + hcol];
    float fv = g4.z + lb[l*G4 + 1024 + hcol];
    float ov = g4.w + lb[l*G4 + 1536 + hcol];
    long coff = ((long)l*256 + bgl)*512 + hcol;
    float cp = cbuf[coff];
    float cn = sigm(fv + 1.f)*cp + sigm(iv)*tanh_(gv);
    float hn = sigm(ov)*tanh_(cn);
    cbuf[coff] = cn;
    hb[(((long)pwr*3 + l)*256 + bgl)*512 + hcol] = f2bf(hn);
    if (l == 2) hcell[bl*8 + hc] = hn;
  }
  if (l == 2){
    __syncthreads();
    #pragma unroll
    for (int q = 0; q < 2; ++q){
      int oid = tid + 256*q;
      int bl = oid >> 4, o = oid & 15;
      float a = 0.f;
      #pragma unroll
      for (int hc = 0; hc < 8; ++hc) a += hcell[bl*8 + hc] * ow[(n*8 + hc)*16 + o];
      atomicAdd(dout + ((long)(bg0 + bl)*T_ + t)*16 + o, a);
    }
  }
}

// ================= launch =================

extern "C" void kernel_launch(void* const* d_in, const int* in_sizes, int n_in,
                              void* d_out, int out_size, void* d_ws, size_t ws_size,
                              hipStream_t stream)
{
  const float* x  = (const float*)d_in[0];
  const float* pw = (const float*)d_in[1];
  const float* pb = (const float*)d_in[2];
  const float* lw = (const float*)d_in[3];
  const float* lb = (const float*)d_in[4];
  const float* ow = (const float*)d_in[5];
  const float* ob = (const float*)d_in[6];
  float* dout = (float*)d_out;

  char* ws = (char*)d_ws;
  size_t off = 0;
  auto carve = [&](size_t bytes){ char* p = ws + off; off += (bytes + 255) & ~(size_t)255; return p; };
  unsigned short* wf    = (unsigned short*)carve(3ull*64*4096*8*2);       // 12.58 MB
  unsigned short* ring  = (unsigned short*)carve(128ull*3*256*512*2);     // 100.66 MB
  unsigned short* xpall = (unsigned short*)carve((size_t)B_*T_*H_*2);     // 33.55 MB
  int*            flags = (int*)carve(256);
  size_t need_lux = off;                                                  // ~146.8 MB

  bool lux = (ws_size >= need_lux);
  if (lux)
    lux = (hipFuncSetAttribute((const void*)k_rnn,
                               hipFuncAttributeMaxDynamicSharedMemorySize,
                               139264) == hipSuccess);

  if (lux){
    hipMemsetAsync(flags, 0, 256, stream);
    k_wconv<<<3072, 256, 0, stream>>>(lw, wf);
    k_xp<<<512, 256, 0, stream>>>(x, pw, pb, xpall);
    k_rnn<<<96, 256, 139264, stream>>>(wf, lb, ring, xpall, flags);
    k_out<<<256, 256, 0, stream>>>(ring, ow, ob, dout);
  } else {
    // round-0 compact fallback (proven, 2199 us)
    size_t o2 = 0;
    auto carve2 = [&](size_t bytes){ char* p = ws + o2; o2 += (bytes + 255) & ~(size_t)255; return p; };
    unsigned short* wf0   = (unsigned short*)carve2(3ull*1024*2048*2);
    float*          cbuf0 = (float*)carve2(3ull*256*512*4);
    unsigned short* hbuf0 = (unsigned short*)carve2(2ull*3*256*512*2);
    hipMemsetAsync(cbuf0, 0, 3ull*256*512*4 + 2ull*3*256*512*2, stream);
    k_wconv0<<<3072, 256, 0, stream>>>(lw, wf0);
    k_iout<<<2048, 256, 0, stream>>>(dout, ob);
    for (int t = 0; t < T_; ++t)
      for (int l = 0; l < 3; ++l)
        k_stage0<<<512, 256, 0, stream>>>(x, pw, pb, wf0, lb, ow, dout,
                                          cbuf0, hbuf0, t, l);
  }
}

// Round 8
// 3044.003 us; speedup vs baseline: 2.2076x; 1.0037x over previous
//
#include <hip/hip_runtime.h>

// RecurrentEncoder: proj(16->512)+relu, 3-layer LSTM (H=512), out head (512->16).
// B=256, T=128. Round 8: ring-buffer persistent kernel (96 WGs x 256 thr, 1 WG/CU,
// W in LDS, c in regs, verified 32x32x16 swapped-operand MFMA, cached ring reads —
// all from round 7) with the sync rewritten: per-WG SLOT flags (single posted
// store per producer, NO fetch_add RMW serialization) polled one-slot-per-lane by
// each wave autonomously (__all reduce, no syncthreads in the wait path). l=0
// computes its xp half before its own-layer wait. hstage padded (bank conflicts),
// k_out spread over 2048 WGs.

typedef __attribute__((ext_vector_type(8)))  short bf16x8;
typedef __attribute__((ext_vector_type(16))) float f32x16;
typedef __attribute__((ext_vector_type(8)))  unsigned short us8;

#define B_  256
#define T_  128
#define FIN 16
#define H_  512
#define G4  2048
#define MF(A,B,C) __builtin_amdgcn_mfma_f32_32x32x16_bf16(A,B,C,0,0,0)

static __device__ __forceinline__ float bf2f(unsigned short u){
  return __uint_as_float(((unsigned)u) << 16);
}
static __device__ __forceinline__ unsigned short f2bf(float f){  // RNE
  unsigned u = __float_as_uint(f);
  u += 0x7fffu + ((u >> 16) & 1u);
  return (unsigned short)(u >> 16);
}
static __device__ __forceinline__ float sigm(float x){ return 1.f/(1.f + __expf(-x)); }
static __device__ __forceinline__ float tanh_(float x){ return 1.f - 2.f/(__expf(2.f*x) + 1.f); }

// Wave-autonomous slot wait: lane i polls slots[i&31]; done when ALL slots >= v.
// sc1 atomic loads (bypass stale L1/L2 for the reused flag addresses); bounded so
// a desync is a wrong answer, never a timeout. The empty asm is a compiler-only
// memory fence: stops cached ring loads from hoisting above the wait.
static __device__ __forceinline__ void wave_wait(const int* slotbase, int v){
  int guard = 0;
  for (;;){
    int s = __hip_atomic_load((const int*)(slotbase + (threadIdx.x & 31)),
                              __ATOMIC_RELAXED, __HIP_MEMORY_SCOPE_AGENT);
    if (__all(s >= v) || guard++ > (1 << 15)) break;
    __builtin_amdgcn_s_sleep(2);
  }
  asm volatile("" ::: "memory");
}

// ================= prep kernels (verified rounds 1-7) =================

// lstm_w fp32 [3][1024][2048] -> bf16, 32x32x16 A-frag order:
// wf[l][Jb=64][s=64][lane=64][e=8]; j' = Jb*32+(lane&31) (j' = hcol*4+gate),
// k = s*16 + (lane>>5)*8 + e.
__global__ __launch_bounds__(256) void k_wconv(const float* __restrict__ w,
                                               unsigned short* __restrict__ wfo){
  long idx = (long)blockIdx.x*256 + threadIdx.x;   // 786432 = 3*64*64*64
  int lane = (int)(idx & 63);
  int s    = (int)((idx >> 6) & 63);
  int Jb   = (int)((idx >> 12) & 63);
  int l    = (int)(idx >> 18);
  int jp = Jb*32 + (lane & 31);
  int co = (jp & 3)*512 + (jp >> 2);       // orig col = gate*512 + hcol
  int k0 = s*16 + (lane >> 5)*8;
  us8 o;
  #pragma unroll
  for (int e = 0; e < 8; ++e)
    o[e] = f2bf(w[((long)(l*1024 + k0 + e))*2048 + co]);
  *(us8*)(wfo + idx*8) = o;
}

// xp = relu(x @ pw + pb) -> bf16, t-major: xpall[t][b][512]
__global__ __launch_bounds__(256) void k_xp(const float* __restrict__ x,
                                            const float* __restrict__ pw,
                                            const float* __restrict__ pb,
                                            unsigned short* __restrict__ xpall){
  __shared__ float sw[FIN*H_];
  __shared__ float sb[H_];
  int tid = threadIdx.x;
  for (int i = tid; i < FIN*H_; i += 256) sw[i] = pw[i];
  for (int i = tid; i < H_;     i += 256) sb[i] = pb[i];
  __syncthreads();
  int r0 = blockIdx.x * 64;
  int c0 = tid * 2;
  for (int rr = 0; rr < 64; ++rr){
    int r = r0 + rr;                       // flat b*T + t
    int b = r >> 7, t = r & 127;
    const float* xr = x + (long)r*FIN;
    float a0 = sb[c0], a1 = sb[c0+1];
    #pragma unroll
    for (int f = 0; f < FIN; ++f){
      float xv = xr[f];
      a0 += xv * sw[f*H_ + c0];
      a1 += xv * sw[f*H_ + c0 + 1];
    }
    ushort2 tmp;
    tmp.x = f2bf(fmaxf(a0, 0.f));
    tmp.y = f2bf(fmaxf(a1, 0.f));
    *(ushort2*)(xpall + ((long)t*256 + b)*512 + c0) = tmp;
  }
}

// y = ring[t][2] @ out_w + out_b ; grid 2048 (16 rows x 16 outs per WG)
__global__ __launch_bounds__(256) void k_out(const unsigned short* __restrict__ ring,
                                             const float* __restrict__ ow,
                                             const float* __restrict__ ob,
                                             float* __restrict__ dout){
  __shared__ float sw[H_*16];
  int tid = threadIdx.x;
  for (int i = tid; i < H_*16; i += 256) sw[i] = ow[i];
  __syncthreads();
  int r0 = blockIdx.x * 16;
  int rr = tid >> 4, o = tid & 15;
  int r = r0 + rr;                          // flat b*T + t
  int b = r >> 7, t = r & 127;
  const us8* hp = (const us8*)(ring + (((long)t*3 + 2)*256 + b)*512);
  float acc = ob[o];
  for (int k8 = 0; k8 < H_/8; ++k8){
    us8 v = hp[k8];
    #pragma unroll
    for (int e = 0; e < 8; ++e) acc += bf2f(v[e]) * sw[(k8*8 + e)*16 + o];
  }
  dout[(long)r*16 + o] = acc;
}

// ================= persistent RNN kernel =================

// cell writes h into LDS staging tile [256 rows][stride 18 shorts] (conflict-free)
#define CELLS(ACC, JB, RF) \
  { _Pragma("unroll") \
    for (int q = 0; q < 4; ++q){ \
      float iv = ACC[4*q+0], gv = ACC[4*q+1], fv = ACC[4*q+2], ov = ACC[4*q+3]; \
      float cp = cst[JB][RF][q]; \
      float cn = sigm(fv + 1.f)*cp + sigm(iv)*tanh_(gv); \
      float hn = sigm(ov)*tanh_(cn); \
      cst[JB][RF][q] = cn; \
      int row = row0 + RF*32 + l31; \
      int hcl = JB*8 + 2*q + l5; \
      hstage[row*18 + hcl] = f2bf(hn); \
    } }

// grid 96 = l(3) x n(32); block 256 (4 waves; wave wv -> rows wv*64..+63).
// LDS: W slice 128 KB + padded h stage 9 KB -> 1 WG/CU, all co-resident.
__global__ __launch_bounds__(256, 1) void k_rnn(
    const unsigned short* __restrict__ wf, const float* __restrict__ lb,
    unsigned short* ring, const unsigned short* __restrict__ xpall,
    int* slots)
{
  extern __shared__ unsigned char Wl[];    // 131072 + 9216
  unsigned short* hstage = (unsigned short*)(Wl + 131072);
  const int tid = threadIdx.x;
  const int wgid = blockIdx.x;
  const int l = wgid >> 5;
  const int n = wgid & 31;
  const int lane = tid & 63;
  const int wv   = tid >> 6;
  const int l5 = lane >> 5, l31 = lane & 31;
  const int row0 = wv * 64;

  // ---- preload W slice into LDS (once) ----
  {
    const us8* src = (const us8*)(wf + ((long)(l*64 + n*2))*4096*8);
    us8* dst = (us8*)Wl;
    for (int i = tid; i < 8192; i += 256) dst[i] = src[i];
  }
  // ---- bias acc-init (D frag: j'_local = (r&3)+8*(r>>2)+4*l5) ----
  f32x16 bias0, bias1;
  #pragma unroll
  for (int r = 0; r < 16; ++r){
    int hc0 = (n*2 + 0)*8 + 2*(r>>2) + l5;
    int hc1 = (n*2 + 1)*8 + 2*(r>>2) + l5;
    bias0[r] = lb[l*G4 + (r&3)*512 + hc0];
    bias1[r] = lb[l*G4 + (r&3)*512 + hc1];
  }
  float cst[2][2][4] = {};                 // register c-state
  __syncthreads();

  const int* sOwn  = slots + l*32;
  const int* sPrev = slots + (l-1)*32;
  int* mySlot = slots + l*32 + n;

  for (int t = 0; t < T_; ++t){
    f32x16 a00 = bias0, a01 = bias0, a10 = bias1, a11 = bias1;

    // ---- l==0: xp left half FIRST (no deps) -> own-layer wait hides under it ----
    if (l == 0){
      const unsigned short* p0 = xpall + (long)t*256*512
                               + ((long)(row0 + l31))*512 + l5*8;
      const unsigned short* p1 = p0 + 32*512;
      #pragma unroll 8
      for (int s = 0; s < 32; ++s){
        bf16x8 w0 = *(const bf16x8*)(Wl + ((s*64 + lane) << 4));
        bf16x8 w1 = *(const bf16x8*)(Wl + ((4096 + s*64 + lane) << 4));
        bf16x8 b0 = *(const bf16x8*)(p0 + s*16);
        bf16x8 b1 = *(const bf16x8*)(p1 + s*16);
        a00 = MF(w0, b0, a00); a01 = MF(w0, b1, a01);
        a10 = MF(w1, b0, a10); a11 = MF(w1, b1, a11);
      }
    }
    // W1: all 32 WGs of own layer finished step t-1 (slot value >= t).
    if (t > 0) wave_wait(sOwn, t);

    // ---- right half: k in [512,1024) = own h[t-1] from ring (cached). t==0: 0.
    if (t > 0){
      const unsigned short* p0 =
          ring + (((long)((t-1)*3 + l))*256 + row0 + l31)*512 + l5*8;
      const unsigned short* p1 = p0 + 32*512;
      #pragma unroll 8
      for (int s = 32; s < 64; ++s){
        bf16x8 w0 = *(const bf16x8*)(Wl + ((s*64 + lane) << 4));
        bf16x8 w1 = *(const bf16x8*)(Wl + ((4096 + s*64 + lane) << 4));
        bf16x8 b0 = *(const bf16x8*)(p0 + (s-32)*16);
        bf16x8 b1 = *(const bf16x8*)(p1 + (s-32)*16);
        a00 = MF(w0, b0, a00); a01 = MF(w0, b1, a01);
        a10 = MF(w1, b0, a10); a11 = MF(w1, b1, a11);
      }
    }
    // ---- l>0: wait layer below done step t, then relu(h[l-1][t]) left half ----
    if (l > 0){
      wave_wait(sPrev, t + 1);
      const unsigned short* p0 = ring + ((long)(t*3 + (l-1)))*256*512
                               + ((long)(row0 + l31))*512 + l5*8;
      const unsigned short* p1 = p0 + 32*512;
      #pragma unroll 8
      for (int s = 0; s < 32; ++s){
        bf16x8 w0 = *(const bf16x8*)(Wl + ((s*64 + lane) << 4));
        bf16x8 w1 = *(const bf16x8*)(Wl + ((4096 + s*64 + lane) << 4));
        bf16x8 b0 = *(const bf16x8*)(p0 + s*16);
        bf16x8 b1 = *(const bf16x8*)(p1 + s*16);
        #pragma unroll
        for (int e = 0; e < 8; ++e){        // relu on bf16: sign bit -> 0
          if (b0[e] < 0) b0[e] = 0;
          if (b1[e] < 0) b1[e] = 0;
        }
        a00 = MF(w0, b0, a00); a01 = MF(w0, b1, a01);
        a10 = MF(w1, b0, a10); a11 = MF(w1, b1, a11);
      }
    }
    // ---- LSTM cell in regs -> LDS h-stage ----
    CELLS(a00, 0, 0)
    CELLS(a01, 0, 1)
    CELLS(a10, 1, 0)
    CELLS(a11, 1, 1)
    __syncthreads();
    // ---- packed 16B write-through stores into ring (2 per thread) ----
    {
      unsigned short* hdst = ring + ((long)(t*3 + l))*256*512 + n*16;
      #pragma unroll
      for (int c = tid; c < 512; c += 256){
        int row = c >> 1, half = c & 1;
        us8 v = *(const us8*)(hstage + row*18 + half*8);
        *(volatile us8*)(hdst + (long)row*512 + half*8) = v;
      }
    }
    __syncthreads();   // per-wave vmcnt drained before barrier -> stores at L3
    if (tid == 0)      // single posted store, no RMW
      __hip_atomic_store(mySlot, t + 1, __ATOMIC_RELAXED, __HIP_MEMORY_SCOPE_AGENT);
  }
}

// ================= round-0 fallback (compact) kernels =================

__global__ __launch_bounds__(256) void k_wconv0(const float* __restrict__ w,
                                                unsigned short* __restrict__ wf){
  long d8 = ((long)blockIdx.x*256 + threadIdx.x) * 8;
  int lane = (int)((d8 >> 3) & 63);
  int s    = (int)((d8 >> 9) & 31);
  int J    = (int)((d8 >> 14) & 127);
  int l    = (int)(d8 >> 21);
  int jj = lane & 15, khi = lane >> 4;
  int jp = J*16 + jj;
  int co = (jp & 3)*512 + (jp >> 2);
  int kbase = s*32 + khi*8;
  us8 o;
  #pragma unroll
  for (int e = 0; e < 8; ++e)
    o[e] = f2bf(w[((long)(l*1024 + kbase + e))*2048 + co]);
  *(us8*)(wf + d8) = o;
}

__global__ void k_iout(float* __restrict__ dout, const float* __restrict__ ob){
  int i = blockIdx.x*256 + threadIdx.x;
  if (i < B_*T_*16) dout[i] = ob[i & 15];
}

__global__ __launch_bounds__(256, 2) void k_stage0(
    const float* __restrict__ x, const float* __restrict__ pw, const float* __restrict__ pb,
    const unsigned short* __restrict__ wf, const float* __restrict__ lb,
    const float* __restrict__ ow, float* __restrict__ dout,
    float* __restrict__ cbuf, unsigned short* __restrict__ hb,
    int t, int l)
{
  __shared__ unsigned char Ab[32*2048];
  __shared__ float gsm[32*36];
  __shared__ float xrow[32*16];
  __shared__ float hcell[32*8];

  const int tid = threadIdx.x;
  const int bid = blockIdx.x;
  const int m = bid >> 6;
  const int n = ((bid & 7) << 3) | ((bid >> 3) & 7);
  const int pwr = t & 1, prd = pwr ^ 1;
  const int bg0 = m * 32;

  {
    const unsigned short* src = hb + (((long)prd*3 + l)*256 + bg0)*512;
    for (int i = 0; i < 8; ++i){
      int cid = tid + 256*i;
      int row = cid >> 6, cc = cid & 63;
      us8 v = *(const us8*)(src + (long)row*512 + cc*8);
      *(us8*)(Ab + ((row*2048 + 1024 + cc*16) ^ ((row & 7) << 4))) = v;
    }
  }
  if (l > 0){
    const unsigned short* src = hb + (((long)pwr*3 + (l-1))*256 + bg0)*512;
    for (int i = 0; i < 8; ++i){
      int cid = tid + 256*i;
      int row = cid >> 6, cc = cid & 63;
      us8 v = *(const us8*)(src + (long)row*512 + cc*8);
      #pragma unroll
      for (int e = 0; e < 8; ++e) v[e] = (v[e] & 0x8000u) ? (unsigned short)0 : v[e];
      *(us8*)(Ab + ((row*2048 + cc*16) ^ ((row & 7) << 4))) = v;
    }
  } else {
    {
      int e2 = tid*2;
      int br = e2 >> 4, f = e2 & 15;
      const float* xr = x + ((long)(bg0 + br)*T_ + t)*FIN;
      xrow[e2] = xr[f]; xrow[e2+1] = xr[f+1];
    }
    __syncthreads();
    for (int i = 0; i < 8; ++i){
      int cid = tid + 256*i;
      int row = cid >> 6, cc = cid & 63;
      int c0 = cc*8;
      us8 vv;
      #pragma unroll
      for (int j = 0; j < 8; ++j){
        float a = pb[c0 + j];
        #pragma unroll
        for (int f = 0; f < FIN; ++f) a += xrow[row*16 + f] * pw[f*H_ + c0 + j];
        vv[j] = f2bf(fmaxf(a, 0.f));
      }
      *(us8*)(Ab + ((row*2048 + cc*16) ^ ((row & 7) << 4))) = vv;
    }
  }
  __syncthreads();

  const int lane = tid & 63, wid = tid >> 6;
  const int wm = wid >> 1, wn = wid & 1;
  const int J = n*2 + wn;
  const int arow = wm*16 + (lane & 15);
  const unsigned abase = (unsigned)arow*2048 + ((lane >> 4) << 4);
  const unsigned axor = (unsigned)((arow & 7) << 4);
  const unsigned short* bp = wf + ((((long)l*128 + J)*32)*64 + lane)*8;

  typedef __attribute__((ext_vector_type(4))) float f32x4;
  f32x4 acc = {0.f, 0.f, 0.f, 0.f};
  #pragma unroll
  for (int s = 0; s < 32; ++s){
    bf16x8 af = *(const bf16x8*)(Ab + ((abase + s*64) ^ axor));
    bf16x8 bfr = *(const bf16x8*)(bp + (long)s*512);
    acc = __builtin_amdgcn_mfma_f32_16x16x32_bf16(af, bfr, acc, 0, 0, 0);
  }
  {
    int colb = wn*16 + (lane & 15);
    int rowb = wm*16 + ((lane >> 4) << 2);
    #pragma unroll
    for (int r = 0; r < 4; ++r) gsm[(rowb + r)*36 + colb] = acc[r];
  }
  __syncthreads();

  {
    int bl = tid >> 3, hc = tid & 7;
    float4 g4 = *(float4*)(&gsm[bl*36 + hc*4]);
    int hcol = n*8 + hc;
    int bgl = bg0 + bl;
    float iv = g4.x + lb[l*G4 + hcol];
    float gv = g4.y + lb[l*G4 + 512 + hcol];
    float fv = g4.z + lb[l*G4 + 1024 + hcol];
    float ov = g4.w + lb[l*G4 + 1536 + hcol];
    long coff = ((long)l*256 + bgl)*512 + hcol;
    float cp = cbuf[coff];
    float cn = sigm(fv + 1.f)*cp + sigm(iv)*tanh_(gv);
    float hn = sigm(ov)*tanh_(cn);
    cbuf[coff] = cn;
    hb[(((long)pwr*3 + l)*256 + bgl)*512 + hcol] = f2bf(hn);
    if (l == 2) hcell[bl*8 + hc] = hn;
  }
  if (l == 2){
    __syncthreads();
    #pragma unroll
    for (int q = 0; q < 2; ++q){
      int oid = tid + 256*q;
      int bl = oid >> 4, o = oid & 15;
      float a = 0.f;
      #pragma unroll
      for (int hc = 0; hc < 8; ++hc) a += hcell[bl*8 + hc] * ow[(n*8 + hc)*16 + o];
      atomicAdd(dout + ((long)(bg0 + bl)*T_ + t)*16 + o, a);
    }
  }
}

// ================= launch =================

extern "C" void kernel_launch(void* const* d_in, const int* in_sizes, int n_in,
                              void* d_out, int out_size, void* d_ws, size_t ws_size,
                              hipStream_t stream)
{
  const float* x  = (const float*)d_in[0];
  const float* pw = (const float*)d_in[1];
  const float* pb = (const float*)d_in[2];
  const float* lw = (const float*)d_in[3];
  const float* lb = (const float*)d_in[4];
  const float* ow = (const float*)d_in[5];
  const float* ob = (const float*)d_in[6];
  float* dout = (float*)d_out;

  char* ws = (char*)d_ws;
  size_t off = 0;
  auto carve = [&](size_t bytes){ char* p = ws + off; off += (bytes + 255) & ~(size_t)255; return p; };
  unsigned short* wf    = (unsigned short*)carve(3ull*64*4096*8*2);       // 12.58 MB
  unsigned short* ring  = (unsigned short*)carve(128ull*3*256*512*2);     // 100.66 MB
  unsigned short* xpall = (unsigned short*)carve((size_t)B_*T_*H_*2);     // 33.55 MB
  int*            slots = (int*)carve(512);                               // 3*32 ints
  size_t need_lux = off;                                                  // ~146.8 MB

  bool lux = (ws_size >= need_lux);
  if (lux)
    lux = (hipFuncSetAttribute((const void*)k_rnn,
                               hipFuncAttributeMaxDynamicSharedMemorySize,
                               140288) == hipSuccess);

  if (lux){
    hipMemsetAsync(slots, 0, 512, stream);
    k_wconv<<<3072, 256, 0, stream>>>(lw, wf);
    k_xp<<<512, 256, 0, stream>>>(x, pw, pb, xpall);
    k_rnn<<<96, 256, 140288, stream>>>(wf, lb, ring, xpall, slots);
    k_out<<<2048, 256, 0, stream>>>(ring, ow, ob, dout);
  } else {
    // round-0 compact fallback (proven, 2199 us)
    size_t o2 = 0;
    auto carve2 = [&](size_t bytes){ char* p = ws + o2; o2 += (bytes + 255) & ~(size_t)255; return p; };
    unsigned short* wf0   = (unsigned short*)carve2(3ull*1024*2048*2);
    float*          cbuf0 = (float*)carve2(3ull*256*512*4);
    unsigned short* hbuf0 = (unsigned short*)carve2(2ull*3*256*512*2);
    hipMemsetAsync(cbuf0, 0, 3ull*256*512*4 + 2ull*3*256*512*2, stream);
    k_wconv0<<<3072, 256, 0, stream>>>(lw, wf0);
    k_iout<<<2048, 256, 0, stream>>>(dout, ob);
    for (int t = 0; t < T_; ++t)
      for (int l = 0; l < 3; ++l)
        k_stage0<<<512, 256, 0, stream>>>(x, pw, pb, wf0, lb, ow, dout,
                                          cbuf0, hbuf0, t, l);
  }
}